// Round 8
// baseline (248.627 us; speedup 1.0000x reference)
//
#include <hip/hip_runtime.h>
#include <hip/hip_bf16.h>
#include <math.h>

#define NV 131072
#define KOFF 27
#define ZROWS 64  // zero-pad region rows (spread hot line)

typedef __attribute__((ext_vector_type(8))) short short8;
typedef __attribute__((ext_vector_type(4))) float floatx4;

__device__ inline float silu_f(float x) { return x / (1.0f + expf(-x)); }

// ---------- fused pre kernel: role-partitioned grid ----------
// [0,512): transpose nbr -> nbr_t as BYTE offsets (row*128), zero-region remap
// [512,2560): LN1+silu -> h0  (64 rows per block — full NV coverage)
// [2560,2992): W1/W2 -> bf16 FRAGMENT-MAJOR Wf[k][ks][n][lane][j]
// [2992,3120): FiLM
// [3120,3122): zero-pad regions of h0/h2
__global__ void pre_kernel(const float* __restrict__ feats, const float* __restrict__ emb,
                           const float* __restrict__ gamma, const float* __restrict__ beta,
                           const float* __restrict__ W1, const float* __restrict__ W2,
                           const float* __restrict__ emb_W, const float* __restrict__ emb_b,
                           const int* __restrict__ nbr,
                           __hip_bfloat16* __restrict__ W1f, __hip_bfloat16* __restrict__ W2f,
                           float* __restrict__ ss, __hip_bfloat16* __restrict__ h0,
                           __hip_bfloat16* __restrict__ h2, unsigned int* __restrict__ nbr_t) {
    int gid = blockIdx.x, tid = threadIdx.x;
    if (gid < 512) {
        __shared__ int s[256 * KOFF];
        int r0 = gid * 256;
        for (int i = tid; i < 256 * KOFF; i += 256) s[i] = nbr[r0 * KOFF + i];
        __syncthreads();
        int r = r0 + tid;
        int zr = NV + ((r >> 7) & (ZROWS - 1));  // spread zero rows
#pragma unroll
        for (int k = 0; k < KOFF; ++k) {
            int v = s[tid * KOFF + k];
            nbr_t[k * NV + r] = (unsigned int)(((v == NV) ? zr : v) << 7);  // byte offset
        }
    } else if (gid < 2560) {
        int wave = tid >> 6, c = tid & 63;
        int base = (gid - 512) * 64;
#pragma unroll 1
        for (int it = 0; it < 16; ++it) {
            int row = base + it * 4 + wave;
            float x = feats[row * 64 + c];
            float s = x;
#pragma unroll
            for (int m = 1; m < 64; m <<= 1) s += __shfl_xor(s, m);
            float mu = s * (1.0f / 64.0f);
            float d = x - mu, q = d * d;
#pragma unroll
            for (int m = 1; m < 64; m <<= 1) q += __shfl_xor(q, m);
            float inv = rsqrtf(q * (1.0f / 64.0f) + 1e-6f);
            h0[row * 64 + c] = __float2bfloat16(silu_f(d * inv * gamma[c] + beta[c]));
        }
    } else if (gid < 2992) {
        int t = (gid - 2560) * 256 + tid;  // < 110592
        // Wf flat index: ((((k*2+ks)*4+n)*64)+lane)*8 + j
        int j = t & 7, lane = (t >> 3) & 63, n = (t >> 9) & 3, ks = (t >> 11) & 1, k = t >> 12;
        int quad = lane >> 4, l15 = lane & 15;
        int cin = ks * 32 + quad * 8 + j;
        int cout = n * 16 + l15;
        int src = k * 4096 + cin * 64 + cout;
        W1f[t] = __float2bfloat16(W1[src]);
        W2f[t] = __float2bfloat16(W2[src]);
    } else if (gid < 3120) {
        int wv = (gid - 2992) * 4 + (tid >> 6);  // 0..511
        int lane = tid & 63;
        int b = wv >> 7, c = wv & 127;
        float acc = 0.0f;
#pragma unroll
        for (int i = 0; i < 8; ++i) {
            int e = i * 64 + lane;
            acc += silu_f(emb[b * 512 + e]) * emb_W[e * 128 + c];
        }
#pragma unroll
        for (int m = 1; m < 64; m <<= 1) acc += __shfl_xor(acc, m);
        if (lane == 0) ss[wv] = acc + emb_b[c];
    } else {
        int t = (gid - 3120) * 256 + tid;
        if (t < ZROWS * 8) {
            short8 z = (short8){0, 0, 0, 0, 0, 0, 0, 0};
            ((short8*)h0)[NV * 8 + t] = z;
            ((short8*)h2)[NV * 8 + t] = z;
        }
    }
}

// ---------- gather-MFMA sparse conv; NO LDS, NO BARRIERS ----------
// B fragments loaded coalesced from fragment-major Wf (L1/L2-resident, shared per CU).
// 32 rows/wave, 128 rows/block, 1024 blocks, 4 waves/SIMD.
template <int EPI>
__global__ __launch_bounds__(256, 4) void conv_kernel(
    const __hip_bfloat16* __restrict__ hsrc,   // [NV+ZROWS, 64] (rows >= NV zero)
    const __hip_bfloat16* __restrict__ Wf,     // [27][2][4][64][8] fragment-major bf16
    const unsigned int* __restrict__ nbr_t,    // [27, NV] byte offsets (row*128)
    const int* __restrict__ batch_idx,         // [NV]
    const float* __restrict__ ss,              // [4, 128]
    const float* __restrict__ bias,            // [64]
    const float* __restrict__ feats,           // [NV, 64] (EPI=1)
    __hip_bfloat16* __restrict__ dst_bf, float* __restrict__ dst_f32) {
    int tid = threadIdx.x, lane = tid & 63, wave = tid >> 6;
    int l15 = lane & 15, quad = lane >> 4;
    int lb = (blockIdx.x & 7) * 128 + (blockIdx.x >> 3);  // XCD-contiguous logical block
    int roww = lb * 128 + wave * 32;

    const char* hb = (const char*)hsrc;
    const char* wfb = (const char*)Wf + lane * 16;  // per-lane base; +k*8192 +(ks*4+n)*1024
    const unsigned int* np = nbr_t + roww + l15;
    unsigned int qoff = (unsigned int)(quad * 16);

    // prologue: idx(0),(1); A(0) gathers
    unsigned int jc0 = np[0], jc1 = np[16];
    unsigned int jn0 = np[NV], jn1 = np[NV + 16];
    unsigned int po0 = jc0 + qoff, po1 = jc1 + qoff;
    short8 ac00 = *(const short8*)(hb + po0);
    short8 ac01 = *(const short8*)(hb + po0 + 64);
    short8 ac10 = *(const short8*)(hb + po1);
    short8 ac11 = *(const short8*)(hb + po1 + 64);

    floatx4 acc[2][4];
#pragma unroll
    for (int m = 0; m < 2; ++m)
#pragma unroll
        for (int n = 0; n < 4; ++n) acc[m][n] = (floatx4){0.f, 0.f, 0.f, 0.f};

#pragma unroll 1
    for (int k = 0; k < KOFF; ++k) {
        // 1. B(k) fragments — coalesced dwordx4, L1-resident (issued first)
        const char* wk = wfb + k * 8192;
        short8 bf00 = *(const short8*)(wk + 0 * 1024);
        short8 bf01 = *(const short8*)(wk + 1 * 1024);
        short8 bf02 = *(const short8*)(wk + 2 * 1024);
        short8 bf03 = *(const short8*)(wk + 3 * 1024);
        short8 bf10 = *(const short8*)(wk + 4 * 1024);
        short8 bf11 = *(const short8*)(wk + 5 * 1024);
        short8 bf12 = *(const short8*)(wk + 6 * 1024);
        short8 bf13 = *(const short8*)(wk + 7 * 1024);
        // 2. A(k+1) gathers (consumed next iter)
        unsigned int o0 = jn0 + qoff, o1 = jn1 + qoff;
        short8 an00 = *(const short8*)(hb + o0);
        short8 an01 = *(const short8*)(hb + o0 + 64);
        short8 an10 = *(const short8*)(hb + o1);
        short8 an11 = *(const short8*)(hb + o1 + 64);
        // 3. idx(k+2)
        int kp2 = (k + 2 < KOFF) ? k + 2 : KOFF - 1;
        unsigned int j20 = np[(size_t)kp2 * NV];
        unsigned int j21 = np[(size_t)kp2 * NV + 16];
        // 4. MFMAs on A(k) (resident since last iter) x B(k)
        acc[0][0] = __builtin_amdgcn_mfma_f32_16x16x32_bf16(ac00, bf00, acc[0][0], 0, 0, 0);
        acc[0][1] = __builtin_amdgcn_mfma_f32_16x16x32_bf16(ac00, bf01, acc[0][1], 0, 0, 0);
        acc[0][2] = __builtin_amdgcn_mfma_f32_16x16x32_bf16(ac00, bf02, acc[0][2], 0, 0, 0);
        acc[0][3] = __builtin_amdgcn_mfma_f32_16x16x32_bf16(ac00, bf03, acc[0][3], 0, 0, 0);
        acc[1][0] = __builtin_amdgcn_mfma_f32_16x16x32_bf16(ac10, bf00, acc[1][0], 0, 0, 0);
        acc[1][1] = __builtin_amdgcn_mfma_f32_16x16x32_bf16(ac10, bf01, acc[1][1], 0, 0, 0);
        acc[1][2] = __builtin_amdgcn_mfma_f32_16x16x32_bf16(ac10, bf02, acc[1][2], 0, 0, 0);
        acc[1][3] = __builtin_amdgcn_mfma_f32_16x16x32_bf16(ac10, bf03, acc[1][3], 0, 0, 0);
        acc[0][0] = __builtin_amdgcn_mfma_f32_16x16x32_bf16(ac01, bf10, acc[0][0], 0, 0, 0);
        acc[0][1] = __builtin_amdgcn_mfma_f32_16x16x32_bf16(ac01, bf11, acc[0][1], 0, 0, 0);
        acc[0][2] = __builtin_amdgcn_mfma_f32_16x16x32_bf16(ac01, bf12, acc[0][2], 0, 0, 0);
        acc[0][3] = __builtin_amdgcn_mfma_f32_16x16x32_bf16(ac01, bf13, acc[0][3], 0, 0, 0);
        acc[1][0] = __builtin_amdgcn_mfma_f32_16x16x32_bf16(ac11, bf10, acc[1][0], 0, 0, 0);
        acc[1][1] = __builtin_amdgcn_mfma_f32_16x16x32_bf16(ac11, bf11, acc[1][1], 0, 0, 0);
        acc[1][2] = __builtin_amdgcn_mfma_f32_16x16x32_bf16(ac11, bf12, acc[1][2], 0, 0, 0);
        acc[1][3] = __builtin_amdgcn_mfma_f32_16x16x32_bf16(ac11, bf13, acc[1][3], 0, 0, 0);
        // 5. rotate pipeline
        ac00 = an00; ac01 = an01; ac10 = an10; ac11 = an11;
        jn0 = j20; jn1 = j21;
    }

    // epilogue: C/D layout col = lane&15, row = quad*4 + r
    float bias_v[4];
#pragma unroll
    for (int n = 0; n < 4; ++n) bias_v[n] = bias[n * 16 + l15];

#pragma unroll
    for (int m = 0; m < 2; ++m) {
#pragma unroll
        for (int r = 0; r < 4; ++r) {
            int row = roww + m * 16 + quad * 4 + r;
            float v[4];
#pragma unroll
            for (int n = 0; n < 4; ++n) v[n] = acc[m][n][r] + bias_v[n];
            if (EPI == 0) {
                float s = v[0] + v[1] + v[2] + v[3];
                float q = v[0] * v[0] + v[1] * v[1] + v[2] * v[2] + v[3] * v[3];
#pragma unroll
                for (int msk = 1; msk < 16; msk <<= 1) {
                    s += __shfl_xor(s, msk);
                    q += __shfl_xor(q, msk);
                }
                float mu = s * (1.0f / 64.0f);
                float var = q * (1.0f / 64.0f) - mu * mu;
                float inv = rsqrtf(var + 1e-6f);
                int b = batch_idx[row];
                const float* sb = ss + b * 128;
#pragma unroll
                for (int n = 0; n < 4; ++n) {
                    float hn = (v[n] - mu) * inv;
                    float x = hn * (1.0f + sb[n * 16 + l15]) + sb[64 + n * 16 + l15];
                    dst_bf[row * 64 + n * 16 + l15] = __float2bfloat16(silu_f(x));
                }
            } else {
#pragma unroll
                for (int n = 0; n < 4; ++n)
                    dst_f32[row * 64 + n * 16 + l15] = v[n] + feats[row * 64 + n * 16 + l15];
            }
        }
    }
}

extern "C" void kernel_launch(void* const* d_in, const int* in_sizes, int n_in,
                              void* d_out, int out_size, void* d_ws, size_t ws_size,
                              hipStream_t stream) {
    (void)in_sizes; (void)n_in; (void)out_size; (void)ws_size;
    const float* feats = (const float*)d_in[0];
    const float* emb   = (const float*)d_in[1];
    const float* gamma = (const float*)d_in[2];
    const float* beta  = (const float*)d_in[3];
    const float* W1    = (const float*)d_in[4];
    const float* b1    = (const float*)d_in[5];
    const float* W2    = (const float*)d_in[6];
    const float* b2    = (const float*)d_in[7];
    const float* emb_W = (const float*)d_in[8];
    const float* emb_b = (const float*)d_in[9];
    const int* nbr     = (const int*)d_in[10];
    const int* bidx    = (const int*)d_in[11];
    float* out = (float*)d_out;

    const size_t HSZ = (size_t)(NV + ZROWS) * 64 * 2;  // bf16 buffer with zero region
    char* ws = (char*)d_ws;
    __hip_bfloat16* W1f = (__hip_bfloat16*)(ws);                  // 221184 B
    __hip_bfloat16* W2f = (__hip_bfloat16*)(ws + 221184);         // 221184 B
    float* ss           = (float*)(ws + 442368);                  // 2048 B
    __hip_bfloat16* h0  = (__hip_bfloat16*)(ws + 444416);
    __hip_bfloat16* h2  = (__hip_bfloat16*)(ws + 444416 + HSZ);
    unsigned int* nbr_t = (unsigned int*)(ws + 444416 + 2 * HSZ); // [27,NV] byte offsets

    pre_kernel<<<3122, 256, 0, stream>>>(feats, emb, gamma, beta, W1, W2, emb_W, emb_b,
                                         nbr, W1f, W2f, ss, h0, h2, nbr_t);
    conv_kernel<0><<<1024, 256, 0, stream>>>(h0, W1f, nbr_t, bidx, ss, b1, nullptr, h2, nullptr);
    conv_kernel<1><<<1024, 256, 0, stream>>>(h2, W2f, nbr_t, bidx, ss, b2, feats, nullptr, out);
}

// Round 9
// 225.186 us; speedup vs baseline: 1.1041x; 1.1041x over previous
//
#include <hip/hip_runtime.h>
#include <hip/hip_bf16.h>
#include <math.h>

#define NV 131072
#define KOFF 27
#define ZROWS 64  // zero-pad region rows (spread hot line)

typedef __attribute__((ext_vector_type(8))) short short8;
typedef __attribute__((ext_vector_type(4))) float floatx4;

__device__ inline float silu_f(float x) { return x / (1.0f + expf(-x)); }

// ---------- fused pre kernel: role-partitioned grid ----------
// [0,512): transpose nbr -> nbr_t as BYTE offsets (row*128), zero-region remap
// [512,2560): LN1+silu -> h0  (64 rows per block — full NV coverage)
// [2560,2992): W1/W2 -> bf16 transposed [k][cout][cin]
// [2992,3120): FiLM
// [3120,3122): zero-pad regions of h0/h2
__global__ void pre_kernel(const float* __restrict__ feats, const float* __restrict__ emb,
                           const float* __restrict__ gamma, const float* __restrict__ beta,
                           const float* __restrict__ W1, const float* __restrict__ W2,
                           const float* __restrict__ emb_W, const float* __restrict__ emb_b,
                           const int* __restrict__ nbr,
                           __hip_bfloat16* __restrict__ W1t, __hip_bfloat16* __restrict__ W2t,
                           float* __restrict__ ss, __hip_bfloat16* __restrict__ h0,
                           __hip_bfloat16* __restrict__ h2, unsigned int* __restrict__ nbr_t) {
    int gid = blockIdx.x, tid = threadIdx.x;
    if (gid < 512) {
        __shared__ int s[256 * KOFF];
        int r0 = gid * 256;
        for (int i = tid; i < 256 * KOFF; i += 256) s[i] = nbr[r0 * KOFF + i];
        __syncthreads();
        int r = r0 + tid;
        int zr = NV + ((r >> 7) & (ZROWS - 1));  // spread zero rows
#pragma unroll
        for (int k = 0; k < KOFF; ++k) {
            int v = s[tid * KOFF + k];
            nbr_t[k * NV + r] = (unsigned int)(((v == NV) ? zr : v) << 7);  // byte offset
        }
    } else if (gid < 2560) {
        int wave = tid >> 6, c = tid & 63;
        int base = (gid - 512) * 64;
#pragma unroll 1
        for (int it = 0; it < 16; ++it) {
            int row = base + it * 4 + wave;
            float x = feats[row * 64 + c];
            float s = x;
#pragma unroll
            for (int m = 1; m < 64; m <<= 1) s += __shfl_xor(s, m);
            float mu = s * (1.0f / 64.0f);
            float d = x - mu, q = d * d;
#pragma unroll
            for (int m = 1; m < 64; m <<= 1) q += __shfl_xor(q, m);
            float inv = rsqrtf(q * (1.0f / 64.0f) + 1e-6f);
            h0[row * 64 + c] = __float2bfloat16(silu_f(d * inv * gamma[c] + beta[c]));
        }
    } else if (gid < 2992) {
        int t = (gid - 2560) * 256 + tid;  // < 110592
        int k = t >> 12, co = (t >> 6) & 63, ci = t & 63;
        int src = k * 4096 + ci * 64 + co;
        W1t[t] = __float2bfloat16(W1[src]);
        W2t[t] = __float2bfloat16(W2[src]);
    } else if (gid < 3120) {
        int wv = (gid - 2992) * 4 + (tid >> 6);  // 0..511
        int lane = tid & 63;
        int b = wv >> 7, c = wv & 127;
        float acc = 0.0f;
#pragma unroll
        for (int i = 0; i < 8; ++i) {
            int e = i * 64 + lane;
            acc += silu_f(emb[b * 512 + e]) * emb_W[e * 128 + c];
        }
#pragma unroll
        for (int m = 1; m < 64; m <<= 1) acc += __shfl_xor(acc, m);
        if (lane == 0) ss[wv] = acc + emb_b[c];
    } else {
        int t = (gid - 3120) * 256 + tid;
        if (t < ZROWS * 8) {
            short8 z = (short8){0, 0, 0, 0, 0, 0, 0, 0};
            ((short8*)h0)[NV * 8 + t] = z;
            ((short8*)h2)[NV * 8 + t] = z;
        }
    }
}

// ---------- gather-MFMA sparse conv; LDS-RESIDENT W (14 k-offsets), barrier-free k-loop ----
// 512 threads (8 waves x 64 rows = 512 rows/block), 256 blocks = 1 block/CU.
// Only 2 __syncthreads per block (around mid-kernel restage of k=14..26).
template <int EPI>
__global__ __launch_bounds__(512, 2) void conv_kernel(
    const __hip_bfloat16* __restrict__ hsrc,   // [NV+ZROWS, 64] (rows >= NV zero)
    const __hip_bfloat16* __restrict__ Wt,     // [27, 64, 64] (k, cout, cin) bf16
    const unsigned int* __restrict__ nbr_t,    // [27, NV] byte offsets (row*128)
    const int* __restrict__ batch_idx,         // [NV]
    const float* __restrict__ ss,              // [4, 128]
    const float* __restrict__ bias,            // [64]
    const float* __restrict__ feats,           // [NV, 64] (EPI=1)
    __hip_bfloat16* __restrict__ dst_bf, float* __restrict__ dst_f32) {
    __shared__ short sW[14 * 4096];  // 112 KB: 14 k-offsets of swizzled 8KB B-tiles
    __shared__ float s_ss[512];

    int tid = threadIdx.x, lane = tid & 63, wave = tid >> 6;
    int l15 = lane & 15, quad = lane >> 4;
    int lb = ((blockIdx.x & 7) << 5) + (blockIdx.x >> 3);  // XCD-contiguous logical block
    int roww = lb * 512 + wave * 64;

    if (EPI == 0) s_ss[tid] = ss[tid];

    const char* hb = (const char*)hsrc;
    const short8* w8 = (const short8*)Wt;  // chunk index: k*512 + c
    char* sb = (char*)sW;

    // swizzled write pos for chunk tid (chunk c -> row*8 + ((c&7)^(row&7)))
    int pw = (((tid >> 3) << 3) + ((tid & 7) ^ ((tid >> 3) & 7))) * 16;
    // read vaddrs: byte = l15*128 + ((ks*4+quad)^(l15&7))*16  (+ n*2048 + k*8192)
    int e7 = l15 & 7;
    int va0 = l15 * 128 + ((quad ^ e7) & 7) * 16;
    int va1 = l15 * 128 + (((4 | quad) ^ e7) & 7) * 16;

    const unsigned int* np = nbr_t + roww + l15;
    unsigned int qoff = (unsigned int)(quad * 16);

    // prologue: idx(0), idx(1); A(0) gathers (in flight across staging)
    unsigned int jn[4];
    short8 ac[4][2];
#pragma unroll
    for (int m = 0; m < 4; ++m) {
        unsigned int jc = np[m * 16];
        unsigned int o = jc + qoff;
        ac[m][0] = *(const short8*)(hb + o);
        ac[m][1] = *(const short8*)(hb + o + 64);
        jn[m] = np[NV + m * 16];
    }

    // stage phase-1 W tiles: k = 0..13
#pragma unroll 1
    for (int kk = 0; kk < 14; ++kk) *(short8*)(sb + kk * 8192 + pw) = w8[kk * 512 + tid];

    floatx4 acc[4][4];
#pragma unroll
    for (int m = 0; m < 4; ++m)
#pragma unroll
        for (int n = 0; n < 4; ++n) acc[m][n] = (floatx4){0.f, 0.f, 0.f, 0.f};

    __syncthreads();

#define CITER(K, KB)                                                                          \
    {                                                                                         \
        int kp2 = ((K) + 2 < KOFF) ? (K) + 2 : KOFF - 1;                                      \
        unsigned int j2[4];                                                                   \
        _Pragma("unroll") for (int m = 0; m < 4; ++m) j2[m] = np[(size_t)kp2 * NV + m * 16];  \
        short8 an[4][2];                                                                      \
        _Pragma("unroll") for (int m = 0; m < 4; ++m) {                                       \
            unsigned int o = jn[m] + qoff;                                                    \
            an[m][0] = *(const short8*)(hb + o);                                              \
            an[m][1] = *(const short8*)(hb + o + 64);                                         \
        }                                                                                     \
        const char* kb = (KB);                                                                \
        short8 bf0[4], bf1[4];                                                                \
        _Pragma("unroll") for (int n = 0; n < 4; ++n)                                         \
            bf0[n] = *(const short8*)(kb + va0 + n * 2048);                                   \
        _Pragma("unroll") for (int n = 0; n < 4; ++n)                                         \
            bf1[n] = *(const short8*)(kb + va1 + n * 2048);                                   \
        _Pragma("unroll") for (int m = 0; m < 4; ++m) {                                       \
            _Pragma("unroll") for (int n = 0; n < 4; ++n)                                     \
                acc[m][n] = __builtin_amdgcn_mfma_f32_16x16x32_bf16(ac[m][0], bf0[n], acc[m][n], 0, 0, 0); \
        }                                                                                     \
        _Pragma("unroll") for (int m = 0; m < 4; ++m) {                                       \
            _Pragma("unroll") for (int n = 0; n < 4; ++n)                                     \
                acc[m][n] = __builtin_amdgcn_mfma_f32_16x16x32_bf16(ac[m][1], bf1[n], acc[m][n], 0, 0, 0); \
        }                                                                                     \
        _Pragma("unroll") for (int m = 0; m < 4; ++m) {                                       \
            ac[m][0] = an[m][0];                                                              \
            ac[m][1] = an[m][1];                                                              \
            jn[m] = j2[m];                                                                    \
        }                                                                                     \
    }

#pragma unroll 1
    for (int k = 0; k < 14; ++k) CITER(k, sb + k * 8192);

    // restage phase-2 W tiles: k = 14..26 (only 2 barriers in the whole kernel)
    __syncthreads();
#pragma unroll 1
    for (int kk = 0; kk < 13; ++kk) *(short8*)(sb + kk * 8192 + pw) = w8[(14 + kk) * 512 + tid];
    __syncthreads();

#pragma unroll 1
    for (int k = 14; k < KOFF; ++k) CITER(k, sb + (k - 14) * 8192);
#undef CITER

    // epilogue: C/D layout col = lane&15, row = quad*4 + r
    float bias_v[4];
#pragma unroll
    for (int n = 0; n < 4; ++n) bias_v[n] = bias[n * 16 + l15];

#pragma unroll
    for (int m = 0; m < 4; ++m) {
#pragma unroll
        for (int r = 0; r < 4; ++r) {
            int row = roww + m * 16 + quad * 4 + r;
            float v[4];
#pragma unroll
            for (int n = 0; n < 4; ++n) v[n] = acc[m][n][r] + bias_v[n];
            if (EPI == 0) {
                float s = v[0] + v[1] + v[2] + v[3];
                float q = v[0] * v[0] + v[1] * v[1] + v[2] * v[2] + v[3] * v[3];
#pragma unroll
                for (int msk = 1; msk < 16; msk <<= 1) {
                    s += __shfl_xor(s, msk);
                    q += __shfl_xor(q, msk);
                }
                float mu = s * (1.0f / 64.0f);
                float var = q * (1.0f / 64.0f) - mu * mu;
                float inv = rsqrtf(var + 1e-6f);
                int b = batch_idx[row];
                const float* sbp = s_ss + b * 128;
#pragma unroll
                for (int n = 0; n < 4; ++n) {
                    float hn = (v[n] - mu) * inv;
                    float x = hn * (1.0f + sbp[n * 16 + l15]) + sbp[64 + n * 16 + l15];
                    dst_bf[row * 64 + n * 16 + l15] = __float2bfloat16(silu_f(x));
                }
            } else {
#pragma unroll
                for (int n = 0; n < 4; ++n)
                    dst_f32[row * 64 + n * 16 + l15] = v[n] + feats[row * 64 + n * 16 + l15];
            }
        }
    }
}

extern "C" void kernel_launch(void* const* d_in, const int* in_sizes, int n_in,
                              void* d_out, int out_size, void* d_ws, size_t ws_size,
                              hipStream_t stream) {
    (void)in_sizes; (void)n_in; (void)out_size; (void)ws_size;
    const float* feats = (const float*)d_in[0];
    const float* emb   = (const float*)d_in[1];
    const float* gamma = (const float*)d_in[2];
    const float* beta  = (const float*)d_in[3];
    const float* W1    = (const float*)d_in[4];
    const float* b1    = (const float*)d_in[5];
    const float* W2    = (const float*)d_in[6];
    const float* b2    = (const float*)d_in[7];
    const float* emb_W = (const float*)d_in[8];
    const float* emb_b = (const float*)d_in[9];
    const int* nbr     = (const int*)d_in[10];
    const int* bidx    = (const int*)d_in[11];
    float* out = (float*)d_out;

    const size_t HSZ = (size_t)(NV + ZROWS) * 64 * 2;  // bf16 buffer with zero region
    char* ws = (char*)d_ws;
    __hip_bfloat16* W1t = (__hip_bfloat16*)(ws);                  // 221184 B
    __hip_bfloat16* W2t = (__hip_bfloat16*)(ws + 221184);         // 221184 B
    float* ss           = (float*)(ws + 442368);                  // 2048 B
    __hip_bfloat16* h0  = (__hip_bfloat16*)(ws + 444416);
    __hip_bfloat16* h2  = (__hip_bfloat16*)(ws + 444416 + HSZ);
    unsigned int* nbr_t = (unsigned int*)(ws + 444416 + 2 * HSZ); // [27,NV] byte offsets

    pre_kernel<<<3122, 256, 0, stream>>>(feats, emb, gamma, beta, W1, W2, emb_W, emb_b,
                                         nbr, W1t, W2t, ss, h0, h2, nbr_t);
    conv_kernel<0><<<256, 512, 0, stream>>>(h0, W1t, nbr_t, bidx, ss, b1, nullptr, h2, nullptr);
    conv_kernel<1><<<256, 512, 0, stream>>>(h2, W2t, nbr_t, bidx, ss, b2, feats, nullptr, out);
}

// Round 10
// 178.863 us; speedup vs baseline: 1.3900x; 1.2590x over previous
//
#include <hip/hip_runtime.h>
#include <hip/hip_bf16.h>
#include <math.h>

#define NV 131072
#define KOFF 27
#define ZROWS 64  // zero-pad region rows (spread hot line)

typedef __attribute__((ext_vector_type(4))) float floatx4;
typedef __attribute__((ext_vector_type(4))) float float4v;
typedef __attribute__((ext_vector_type(2))) unsigned long ulong2v;
typedef __attribute__((ext_vector_type(4))) unsigned int uint4v;

__device__ inline float silu_f(float x) { return x / (1.0f + expf(-x)); }
__device__ inline unsigned int fp8_byte(float x) {
    return __builtin_amdgcn_cvt_pk_fp8_f32(x, x, 0, false) & 0xFF;
}

// h fp8 row layout (64 B): byte quad*16 + half*8 + j  <->  channel half*32 + quad*8 + j
// So a 16-B load at quad*16 gives (av.x = ks0 fragment, av.y = ks1 fragment).

// ---------- fused pre kernel: role-partitioned grid ----------
// [0,512): transpose nbr -> nbr_t as BYTE offsets (row*64), zero-region remap
// [512,8704): LN1+silu -> h0 fp8 (16 lanes/row, 16 rows/block)
// [8704,8812): W1/W2 -> fp8 [k][cout][cin]
// [8812,8940): FiLM
// [8940]: zero-pad regions of h0/h2
__global__ void pre_kernel(const float* __restrict__ feats, const float* __restrict__ emb,
                           const float* __restrict__ gamma, const float* __restrict__ beta,
                           const float* __restrict__ W1, const float* __restrict__ W2,
                           const float* __restrict__ emb_W, const float* __restrict__ emb_b,
                           const int* __restrict__ nbr,
                           unsigned char* __restrict__ W1f, unsigned char* __restrict__ W2f,
                           float* __restrict__ ss, unsigned char* __restrict__ h0,
                           unsigned char* __restrict__ h2, unsigned int* __restrict__ nbr_t) {
    int gid = blockIdx.x, tid = threadIdx.x;
    if (gid < 512) {
        __shared__ int s[256 * KOFF];
        int r0 = gid * 256;
        for (int i = tid; i < 256 * KOFF; i += 256) s[i] = nbr[r0 * KOFF + i];
        __syncthreads();
        int r = r0 + tid;
        int zr = NV + ((r >> 7) & (ZROWS - 1));  // spread zero rows
#pragma unroll
        for (int k = 0; k < KOFF; ++k) {
            int v = s[tid * KOFF + k];
            nbr_t[k * NV + r] = (unsigned int)(((v == NV) ? zr : v) << 6);  // byte offset (64 B rows)
        }
    } else if (gid < 8704) {
        int row = (gid - 512) * 16 + (tid >> 4);
        int t = tid & 15;
        float4v x = ((const float4v*)feats)[row * 16 + t];
        float s = x.x + x.y + x.z + x.w;
#pragma unroll
        for (int m = 1; m < 16; m <<= 1) s += __shfl_xor(s, m);
        float mu = s * (1.0f / 64.0f);
        float d0 = x.x - mu, d1 = x.y - mu, d2 = x.z - mu, d3 = x.w - mu;
        float q = d0 * d0 + d1 * d1 + d2 * d2 + d3 * d3;
#pragma unroll
        for (int m = 1; m < 16; m <<= 1) q += __shfl_xor(q, m);
        float inv = rsqrtf(q * (1.0f / 64.0f) + 1e-6f);
        float4v g = ((const float4v*)gamma)[t], b = ((const float4v*)beta)[t];
        float v0 = silu_f(d0 * inv * g.x + b.x);
        float v1 = silu_f(d1 * inv * g.y + b.y);
        float v2 = silu_f(d2 * inv * g.z + b.z);
        float v3 = silu_f(d3 * inv * g.w + b.w);
        unsigned int pk = __builtin_amdgcn_cvt_pk_fp8_f32(v0, v1, 0, false);
        pk = __builtin_amdgcn_cvt_pk_fp8_f32(v2, v3, pk, true);
        // channels 4t..4t+3 -> permuted dword position
        int pos = ((t >> 1) & 3) * 16 + (t >> 3) * 8 + (t & 1) * 4;
        *(unsigned int*)(h0 + row * 64 + pos) = pk;
    } else if (gid < 8812) {
        int t = (gid - 8704) * 256 + tid;  // dword idx < 27648
        if (t < 27648) {
            int k = t >> 10, rem = t & 1023, cout = rem >> 4, ci4 = (rem & 15) * 4;
            const float* wsrc1 = W1 + k * 4096 + ci4 * 64 + cout;
            const float* wsrc2 = W2 + k * 4096 + ci4 * 64 + cout;
            unsigned int p1 = __builtin_amdgcn_cvt_pk_fp8_f32(wsrc1[0], wsrc1[64], 0, false);
            p1 = __builtin_amdgcn_cvt_pk_fp8_f32(wsrc1[128], wsrc1[192], p1, true);
            unsigned int p2 = __builtin_amdgcn_cvt_pk_fp8_f32(wsrc2[0], wsrc2[64], 0, false);
            p2 = __builtin_amdgcn_cvt_pk_fp8_f32(wsrc2[128], wsrc2[192], p2, true);
            ((unsigned int*)W1f)[t] = p1;
            ((unsigned int*)W2f)[t] = p2;
        }
    } else if (gid < 8940) {
        int wv = (gid - 8812) * 4 + (tid >> 6);  // 0..511
        int lane = tid & 63;
        int b = wv >> 7, c = wv & 127;
        float acc = 0.0f;
#pragma unroll
        for (int i = 0; i < 8; ++i) {
            int e = i * 64 + lane;
            acc += silu_f(emb[b * 512 + e]) * emb_W[e * 128 + c];
        }
#pragma unroll
        for (int m = 1; m < 64; m <<= 1) acc += __shfl_xor(acc, m);
        if (lane == 0) ss[wv] = acc + emb_b[c];
    } else {
        if (tid < 256) {  // ZROWS*64 = 4096 B each
            uint4v z = (uint4v){0, 0, 0, 0};
            ((uint4v*)(h0 + NV * 64))[tid] = z;
            ((uint4v*)(h2 + NV * 64))[tid] = z;
        }
    }
}

// ---------- gather-MFMA sparse conv, fp8 A/B ----------
// 64 rows/wave, 256 rows/block, 512 blocks; W fp8 in LDS (stride-72 rows, dbuf).
template <int EPI>
__global__ __launch_bounds__(256, 2) void conv_kernel(
    const unsigned char* __restrict__ hsrc,    // [NV+ZROWS, 64B] fp8 permuted rows
    const unsigned char* __restrict__ Wf,      // [27][64][64] fp8 (k, cout, cin)
    const unsigned int* __restrict__ nbr_t,    // [27, NV] byte offsets (row*64)
    const int* __restrict__ batch_idx,         // [NV]
    const float* __restrict__ ss,              // [4, 128]
    const float* __restrict__ bias,            // [64]
    const float* __restrict__ feats,           // [NV, 64] (EPI=1)
    unsigned char* __restrict__ dst_f8, float* __restrict__ dst_f32) {
    __shared__ char sW[2 * 4608];  // two W buffers, 64 rows x 72 B (8B pad kills conflicts)
    __shared__ float s_ss[512];

    int tid = threadIdx.x, lane = tid & 63, wave = tid >> 6;
    int l15 = lane & 15, quad = lane >> 4;
    int lb = (blockIdx.x & 7) * 64 + (blockIdx.x >> 3);  // XCD-contiguous logical block
    int roww = lb * 256 + wave * 64;

    if (EPI == 0) {
        s_ss[tid] = ss[tid];
        s_ss[tid + 256] = ss[tid + 256];
    }

    const char* hb = (const char*)hsrc;
    const ulong2v* w16 = (const ulong2v*)Wf;  // 16B chunks: k*256 + c
    char* sbase = (char*)sW;

    // staging: chunk c (=tid) -> LDS row c>>2 (stride 72), 16B slot c&3
    int pw = (tid >> 2) * 72 + (tid & 3) * 16;
    // B read addr: cout*72 + ks*32 + quad*8   (cout = n*16 + l15)
    int vb = l15 * 72 + quad * 8;

    const unsigned int* np = nbr_t + roww + l15;
    unsigned int qoff = (unsigned int)(quad * 16);

    // prologue: idx(0),(1); A(0); W(0)->LDS; W(1)->regs
    unsigned int jn[4];
    ulong2v ac[4];
#pragma unroll
    for (int m = 0; m < 4; ++m) {
        unsigned int jc = np[m * 16];
        ac[m] = *(const ulong2v*)(hb + jc + qoff);
        jn[m] = np[NV + m * 16];
    }
    *(ulong2v*)(sbase + pw) = w16[tid];
    ulong2v Br = w16[256 + tid];

    floatx4 acc[4][4];
#pragma unroll
    for (int m = 0; m < 4; ++m)
#pragma unroll
        for (int n = 0; n < 4; ++n) acc[m][n] = (floatx4){0.f, 0.f, 0.f, 0.f};

    __asm__ __volatile__("s_waitcnt lgkmcnt(0)" ::: "memory");
    __builtin_amdgcn_s_barrier();

#define CITER(K, CURB, OTHB)                                                                  \
    {                                                                                         \
        int kp2 = ((K) + 2 < KOFF) ? (K) + 2 : KOFF - 1;                                      \
        ulong2v Bn = w16[kp2 * 256 + tid];                                                    \
        unsigned int j2[4];                                                                   \
        _Pragma("unroll") for (int m = 0; m < 4; ++m) j2[m] = np[(size_t)kp2 * NV + m * 16];  \
        ulong2v an[4];                                                                        \
        _Pragma("unroll") for (int m = 0; m < 4; ++m)                                         \
            an[m] = *(const ulong2v*)(hb + jn[m] + qoff);                                     \
        long bf0[4], bf1[4];                                                                  \
        _Pragma("unroll") for (int n = 0; n < 4; ++n)                                         \
            bf0[n] = *(const long*)(sbase + (CURB) + vb + n * 1152);                          \
        _Pragma("unroll") for (int n = 0; n < 4; ++n)                                         \
            bf1[n] = *(const long*)(sbase + (CURB) + vb + n * 1152 + 32);                     \
        *(ulong2v*)(sbase + (OTHB) + pw) = Br;                                                \
        _Pragma("unroll") for (int m = 0; m < 4; ++m) {                                       \
            long a0 = (long)ac[m].x;                                                          \
            _Pragma("unroll") for (int n = 0; n < 4; ++n)                                     \
                acc[m][n] = __builtin_amdgcn_mfma_f32_16x16x32_fp8_fp8(a0, bf0[n], acc[m][n], 0, 0, 0); \
        }                                                                                     \
        _Pragma("unroll") for (int m = 0; m < 4; ++m) {                                       \
            long a1 = (long)ac[m].y;                                                          \
            _Pragma("unroll") for (int n = 0; n < 4; ++n)                                     \
                acc[m][n] = __builtin_amdgcn_mfma_f32_16x16x32_fp8_fp8(a1, bf1[n], acc[m][n], 0, 0, 0); \
        }                                                                                     \
        __asm__ __volatile__("s_waitcnt lgkmcnt(0)" ::: "memory");                            \
        __builtin_amdgcn_s_barrier();                                                         \
        _Pragma("unroll") for (int m = 0; m < 4; ++m) {                                       \
            ac[m] = an[m];                                                                    \
            jn[m] = j2[m];                                                                    \
        }                                                                                     \
        Br = Bn;                                                                              \
    }

#pragma unroll 1
    for (int k = 0; k < KOFF - 1; k += 2) {
        CITER(k, 0, 4608);
        CITER(k + 1, 4608, 0);
    }
    CITER(KOFF - 1, 0, 4608);
#undef CITER

    // epilogue: C/D layout col = lane&15, row = quad*4 + r
    float bias_v[4];
#pragma unroll
    for (int n = 0; n < 4; ++n) bias_v[n] = bias[n * 16 + l15];

#pragma unroll
    for (int m = 0; m < 4; ++m) {
#pragma unroll
        for (int r = 0; r < 4; ++r) {
            int row = roww + m * 16 + quad * 4 + r;
            float v[4];
#pragma unroll
            for (int n = 0; n < 4; ++n) v[n] = acc[m][n][r] + bias_v[n];
            if (EPI == 0) {
                float s = v[0] + v[1] + v[2] + v[3];
                float q = v[0] * v[0] + v[1] * v[1] + v[2] * v[2] + v[3] * v[3];
#pragma unroll
                for (int msk = 1; msk < 16; msk <<= 1) {
                    s += __shfl_xor(s, msk);
                    q += __shfl_xor(q, msk);
                }
                float mu = s * (1.0f / 64.0f);
                float var = q * (1.0f / 64.0f) - mu * mu;
                float inv = rsqrtf(var + 1e-6f);
                int b = batch_idx[row];
                const float* sbp = s_ss + b * 128;
#pragma unroll
                for (int n = 0; n < 4; ++n) {
                    float hn = (v[n] - mu) * inv;
                    float x = silu_f(hn * (1.0f + sbp[n * 16 + l15]) + sbp[64 + n * 16 + l15]);
                    // channel c = n*16+l15 -> permuted byte pos
                    int c = n * 16 + l15;
                    int pos = (((c >> 3) & 3) << 4) + ((c >> 5) << 3) + (c & 7);
                    dst_f8[row * 64 + pos] = (unsigned char)fp8_byte(x);
                }
            } else {
#pragma unroll
                for (int n = 0; n < 4; ++n)
                    dst_f32[row * 64 + n * 16 + l15] = v[n] + feats[row * 64 + n * 16 + l15];
            }
        }
    }
}

extern "C" void kernel_launch(void* const* d_in, const int* in_sizes, int n_in,
                              void* d_out, int out_size, void* d_ws, size_t ws_size,
                              hipStream_t stream) {
    (void)in_sizes; (void)n_in; (void)out_size; (void)ws_size;
    const float* feats = (const float*)d_in[0];
    const float* emb   = (const float*)d_in[1];
    const float* gamma = (const float*)d_in[2];
    const float* beta  = (const float*)d_in[3];
    const float* W1    = (const float*)d_in[4];
    const float* b1    = (const float*)d_in[5];
    const float* W2    = (const float*)d_in[6];
    const float* b2    = (const float*)d_in[7];
    const float* emb_W = (const float*)d_in[8];
    const float* emb_b = (const float*)d_in[9];
    const int* nbr     = (const int*)d_in[10];
    const int* bidx    = (const int*)d_in[11];
    float* out = (float*)d_out;

    const size_t HSZ = (size_t)(NV + ZROWS) * 64;  // fp8 buffer with zero region
    char* ws = (char*)d_ws;
    unsigned char* W1f  = (unsigned char*)(ws);                   // 110592 B
    unsigned char* W2f  = (unsigned char*)(ws + 110592);          // 110592 B
    float* ss           = (float*)(ws + 221184);                  // 2048 B
    unsigned char* h0   = (unsigned char*)(ws + 223232);
    unsigned char* h2   = (unsigned char*)(ws + 223232 + HSZ);
    unsigned int* nbr_t = (unsigned int*)(ws + 223232 + 2 * HSZ); // [27,NV] byte offsets

    pre_kernel<<<8941, 256, 0, stream>>>(feats, emb, gamma, beta, W1, W2, emb_W, emb_b,
                                         nbr, W1f, W2f, ss, h0, h2, nbr_t);
    conv_kernel<0><<<512, 256, 0, stream>>>(h0, W1f, nbr_t, bidx, ss, b1, nullptr, h2, nullptr);
    conv_kernel<1><<<512, 256, 0, stream>>>(h2, W2f, nbr_t, bidx, ss, b2, feats, nullptr, out);
}